// Round 15
// baseline (298.706 us; speedup 1.0000x reference)
//
#include <hip/hip_runtime.h>
#include <hip/hip_bf16.h>

#define NN 100000
#define NE 1600000
#define DD 64
#define NG 256
#define SHIFT 8     // 256 nodes per bucket
#define NBK 391     // ceil(NN/256)
#define BCAP 4608   // bucket capacity: mean 4092, +8 sigma
#define NSB 256     // scatter blocks
#define CHUNK 6250  // edges per scatter block
#define FB 1563     // fused blocks: ceil(NN/64)

typedef __attribute__((ext_vector_type(8))) short bf16x8;
typedef __attribute__((ext_vector_type(4))) float f32x4;
typedef __attribute__((ext_vector_type(8))) unsigned short ushort8v;

__device__ __forceinline__ float b2f(ushort u){
  unsigned v = ((unsigned)u) << 16;
  return __uint_as_float(v);
}
__device__ __forceinline__ ushort f2b(float f){
  __hip_bfloat16 b = __float2bfloat16(f);
  return *(ushort*)&b;
}

// ---------------- weight packing + gcur init (fused) ----------------
// wp layout per layer: [s(2)][t(8)][lane(64)][j(8)] bf16
// value = W[k][col], k = s*32 + (lane>>4)*8 + j, col = t*16 + (lane&15)
__global__ void k_wpack3(const float* __restrict__ Wr1, const float* __restrict__ Wo1,
                         const float* __restrict__ Wr2, const float* __restrict__ Wo2,
                         const float* __restrict__ Wr3, const float* __restrict__ Wo3,
                         ushort* __restrict__ wp, int* __restrict__ gcur){
  int i = blockIdx.x*256 + threadIdx.x;
  if (i < NBK) gcur[i] = i*BCAP;          // fixed bucket bases
  if (i >= 3*8192) return;
  int lay = i >> 13;
  int r = i & 8191;
  int j = r & 7, l = (r>>3) & 63, t = (r>>9) & 7, s = r >> 12;
  int k = s*32 + ((l>>4)<<3) + j;
  int col = t*16 + (l&15);
  const float* Wrel  = (lay==0) ? Wr1 : (lay==1) ? Wr2 : Wr3;
  const float* Wroot = (lay==0) ? Wo1 : (lay==1) ? Wo2 : Wo3;
  float v = (col < 64) ? Wrel[k*64 + col] : Wroot[k*64 + (col-64)];
  wp[i] = f2b(v);
}

// ---------------- scatter: per-block hist -> reserve -> write packed edges ----------------
__global__ __launch_bounds__(256) void k_bscatter(const int* __restrict__ src, const int* __restrict__ dst,
                           int* __restrict__ gcur, unsigned* __restrict__ ebuf){
  __shared__ int h[NBK];
  __shared__ int base[NBK];
  __shared__ int lcur[NBK];
  for (int i=threadIdx.x; i<NBK; i+=256) h[i]=0;
  __syncthreads();
  const int e0 = blockIdx.x*CHUNK;
  const int e1 = min(e0+CHUNK, NE);
  for (int e=e0+threadIdx.x; e<e1; e+=256) atomicAdd(&h[dst[e]>>SHIFT], 1);
  __syncthreads();
  for (int i=threadIdx.x; i<NBK; i+=256){
    base[i] = h[i] ? atomicAdd(&gcur[i], h[i]) : 0;
    lcur[i] = 0;
  }
  __syncthreads();
  for (int e=e0+threadIdx.x; e<e1; e+=256){
    int d = dst[e];
    int b = d >> SHIFT;
    int r = atomicAdd(&lcur[b], 1);
    size_t idx = (size_t)base[b] + r;
    if (idx < (size_t)NBK*BCAP)
      ebuf[idx] = ((unsigned)(d & 255) << 17) | (unsigned)src[e];   // 8b local-dst | 17b src
  }
}

// ---------------- per-bucket LDS counting sort -> bucket-padded CSR + rowptr + deg ----------------
__global__ __launch_bounds__(256) void k_bfill(const unsigned* __restrict__ ebuf, const int* __restrict__ gcur,
                        int* __restrict__ rowptr, int* __restrict__ degarr, int* __restrict__ csr){
  __shared__ int c[256];
  __shared__ int lcur[256];
  __shared__ int s[256];
  __shared__ int scnt;
  const int b = blockIdx.x, t = threadIdx.x;
  const int ebase = b*BCAP;
  if (t == 0) scnt = min(gcur[b] - ebase, BCAP);
  c[t] = 0;
  __syncthreads();
  const int cnt = scnt;
  for (int i=t; i<cnt; i+=256) atomicAdd(&c[ebuf[ebase+i]>>17], 1);
  __syncthreads();
  int v = c[t];
  s[t] = v;
  __syncthreads();
  for (int off=1; off<256; off<<=1){
    int u = (t >= off) ? s[t-off] : 0;
    __syncthreads();
    s[t] += u;
    __syncthreads();
  }
  int excl = s[t] - v;
  lcur[t] = excl;
  int node = (b << SHIFT) + t;
  if (node < NN){ rowptr[node] = ebase + excl; degarr[node] = v; }
  __syncthreads();
  for (int i=t; i<cnt; i+=256){
    unsigned p = ebuf[ebase+i];
    int dl = (int)(p >> 17);
    int r = atomicAdd(&lcur[dl], 1);
    csr[ebase + r] = (int)(p & 0x1FFFFu);
  }
}

// ---------------- MFMA dual GEMM (layer 1, global A): [Y | R] = A @ [Wrel | Wroot] ----------------
#define CPAD 136   // ct row pad (ushorts): 272B
__global__ __launch_bounds__(256) void k_gemm_mfma(const float* __restrict__ Af,
    const ushort* __restrict__ wp, ushort* __restrict__ Y, ushort* __restrict__ Rr){
  __shared__ ushort ct[64*CPAD];   // 17408 B
  const int tid = threadIdx.x;
  const int w = tid >> 6, l = tid & 63;
  const int m = l & 15, kg = l >> 4;
  const int row0 = blockIdx.x*64;
  int arow = row0 + w*16 + m; if (arow >= NN) arow = NN-1;   // clamp; stores guarded
  bf16x8 a0, a1;
  {
    float4 f0 = *(const float4*)&Af[(size_t)arow*64 + kg*8];
    float4 f1 = *(const float4*)&Af[(size_t)arow*64 + kg*8 + 4];
    float4 f2 = *(const float4*)&Af[(size_t)arow*64 + 32 + kg*8];
    float4 f3 = *(const float4*)&Af[(size_t)arow*64 + 32 + kg*8 + 4];
    a0[0]=(short)f2b(f0.x); a0[1]=(short)f2b(f0.y); a0[2]=(short)f2b(f0.z); a0[3]=(short)f2b(f0.w);
    a0[4]=(short)f2b(f1.x); a0[5]=(short)f2b(f1.y); a0[6]=(short)f2b(f1.z); a0[7]=(short)f2b(f1.w);
    a1[0]=(short)f2b(f2.x); a1[1]=(short)f2b(f2.y); a1[2]=(short)f2b(f2.z); a1[3]=(short)f2b(f2.w);
    a1[4]=(short)f2b(f3.x); a1[5]=(short)f2b(f3.y); a1[6]=(short)f2b(f3.z); a1[7]=(short)f2b(f3.w);
  }
  #pragma unroll
  for (int t=0; t<8; t++){
    bf16x8 b0 = *(const bf16x8*)&wp[((size_t)(0*8+t)*64 + l)*8];
    bf16x8 b1 = *(const bf16x8*)&wp[((size_t)(1*8+t)*64 + l)*8];
    f32x4 c = {0.f, 0.f, 0.f, 0.f};
    c = __builtin_amdgcn_mfma_f32_16x16x32_bf16(a0, b0, c, 0, 0, 0);
    c = __builtin_amdgcn_mfma_f32_16x16x32_bf16(a1, b1, c, 0, 0, 0);
    #pragma unroll
    for (int reg=0; reg<4; reg++){
      int lrow = w*16 + kg*4 + reg;     // D: row=(lane>>4)*4+reg, col=lane&15
      ct[lrow*CPAD + t*16 + m] = f2b(c[reg]);
    }
  }
  __syncthreads();
  #pragma unroll
  for (int u=0; u<4; u++){
    int i = tid + u*256;               // 0..1023
    int lrow = i >> 4, cb = i & 15;
    int grow = row0 + lrow;
    if (grow < NN){
      ushort8v v = *(const ushort8v*)&ct[lrow*CPAD + cb*8];
      if (cb < 8) *(ushort8v*)&Y [(size_t)grow*64 + cb*8]       = v;
      else        *(ushort8v*)&Rr[(size_t)grow*64 + (cb-8)*8]   = v;
    }
  }
}

// ---------------- fused: aggr(64 nodes -> LDS h) + gemm(next layer) ----------------
// Phase A: each wave aggregates 16 nodes (8 lanes/edge, 16 loads in flight), relu, h -> LDS.
// Phase B: MFMA on LDS h-tile -> Yn,Rn (ct overlay, coalesced stores). h never hits global.
__global__ __launch_bounds__(256) void k_fused(
    const ushort* __restrict__ Y, const ushort* __restrict__ R,
    const float* __restrict__ brel,
    const int* __restrict__ rowptr, const int* __restrict__ degarr,
    const int* __restrict__ csr,
    const ushort* __restrict__ wpn, ushort* __restrict__ Yn, ushort* __restrict__ Rn){
  __shared__ union { ushort sh[64][72]; ushort ct[64*CPAD]; } sm;  // 17408 B
  const int tid = threadIdx.x;
  const int wv = tid >> 6, lane = tid & 63;
  const int g = lane >> 3, c8 = (lane & 7) << 3;
  const int nbase = blockIdx.x * 64;
  // Phase A
  for (int it = 0; it < 16; ++it){
    int node = nbase + wv*16 + it;
    if (node < NN){
      int beg = rowptr[node];
      int dc = degarr[node];
      const int* lst = csr + beg;
      float a[8] = {0.f,0.f,0.f,0.f,0.f,0.f,0.f,0.f};
      int i = g;
      for (; i + 8 < dc; i += 16){
        int s0 = lst[i], s1 = lst[i+8];
        ushort8v y0 = *(const ushort8v*)&Y[((size_t)s0<<6) + c8];
        ushort8v y1 = *(const ushort8v*)&Y[((size_t)s1<<6) + c8];
        #pragma unroll
        for (int j=0;j<8;j++) a[j] += b2f(y0[j]) + b2f(y1[j]);
      }
      if (i < dc){
        int s0 = lst[i];
        ushort8v y0 = *(const ushort8v*)&Y[((size_t)s0<<6) + c8];
        #pragma unroll
        for (int j=0;j<8;j++) a[j] += b2f(y0[j]);
      }
      #pragma unroll
      for (int j=0;j<8;j++){
        a[j] += __shfl_xor(a[j], 8);
        a[j] += __shfl_xor(a[j], 16);
        a[j] += __shfl_xor(a[j], 32);
      }
      if (g == 0){
        ushort8v r8 = *(const ushort8v*)&R[((size_t)node<<6) + c8];
        float4 b0 = *(const float4*)&brel[c8];
        float4 b1 = *(const float4*)&brel[c8+4];
        float bb[8] = {b0.x,b0.y,b0.z,b0.w,b1.x,b1.y,b1.z,b1.w};
        ushort8v o;
        #pragma unroll
        for (int j=0;j<8;j++){
          float v = a[j] + b2f(r8[j]) + bb[j];
          o[j] = f2b(fmaxf(v, 0.f));   // fused layers always relu
        }
        *(ushort8v*)&sm.sh[wv*16 + it][c8] = o;
      }
    }
  }
  __syncthreads();
  // Phase B: A-frags from LDS (rows this wave just computed)
  const int m = lane & 15, kg = lane >> 4;
  bf16x8 a0 = *(const bf16x8*)&sm.sh[wv*16 + m][kg*8];
  bf16x8 a1 = *(const bf16x8*)&sm.sh[wv*16 + m][32 + kg*8];
  __syncthreads();                     // before ct overlay
  #pragma unroll
  for (int t=0; t<8; t++){
    bf16x8 b0 = *(const bf16x8*)&wpn[((size_t)(0*8+t)*64 + lane)*8];
    bf16x8 b1 = *(const bf16x8*)&wpn[((size_t)(1*8+t)*64 + lane)*8];
    f32x4 c = {0.f,0.f,0.f,0.f};
    c = __builtin_amdgcn_mfma_f32_16x16x32_bf16(a0, b0, c, 0, 0, 0);
    c = __builtin_amdgcn_mfma_f32_16x16x32_bf16(a1, b1, c, 0, 0, 0);
    #pragma unroll
    for (int reg=0; reg<4; reg++){
      int lrow = wv*16 + kg*4 + reg;
      sm.ct[lrow*CPAD + t*16 + m] = f2b(c[reg]);
    }
  }
  __syncthreads();
  #pragma unroll
  for (int u=0; u<4; u++){
    int i = tid + u*256;
    int lrow = i >> 4, cb = i & 15;
    int grow = nbase + lrow;
    if (grow < NN){
      ushort8v v = *(const ushort8v*)&sm.ct[lrow*CPAD + cb*8];
      if (cb < 8) *(ushort8v*)&Yn[(size_t)grow*64 + cb*8]     = v;
      else        *(ushort8v*)&Rn[(size_t)grow*64 + (cb-8)*8] = v;
    }
  }
}

// ---------------- final gather-aggregate (layer 3, no relu, h -> global) ----------------
__global__ __launch_bounds__(256) void k_aggr(const ushort* __restrict__ Y,
    const ushort* __restrict__ R, const float* __restrict__ brel,
    const int* __restrict__ rowptr, const int* __restrict__ degarr, const int* __restrict__ csr,
    ushort* __restrict__ hout){
  int node = blockIdx.x*4 + (threadIdx.x>>6);
  if (node >= NN) return;
  int lane = threadIdx.x & 63;
  int g = lane >> 3;
  int c8 = (lane & 7) << 3;
  int beg = rowptr[node];
  int dc = degarr[node];
  const int* lst = csr + beg;
  float a[8] = {0.f,0.f,0.f,0.f,0.f,0.f,0.f,0.f};
  int i = g;
  for (; i + 8 < dc; i += 16){
    int s0 = lst[i], s1 = lst[i+8];
    ushort8v y0 = *(const ushort8v*)&Y[((size_t)s0<<6) + c8];
    ushort8v y1 = *(const ushort8v*)&Y[((size_t)s1<<6) + c8];
    #pragma unroll
    for (int j=0;j<8;j++) a[j] += b2f(y0[j]) + b2f(y1[j]);
  }
  if (i < dc){
    int s0 = lst[i];
    ushort8v y0 = *(const ushort8v*)&Y[((size_t)s0<<6) + c8];
    #pragma unroll
    for (int j=0;j<8;j++) a[j] += b2f(y0[j]);
  }
  #pragma unroll
  for (int j=0;j<8;j++){
    a[j] += __shfl_xor(a[j], 8);
    a[j] += __shfl_xor(a[j], 16);
    a[j] += __shfl_xor(a[j], 32);
  }
  if (g == 0){
    ushort8v r8 = *(const ushort8v*)&R[((size_t)node<<6) + c8];
    float4 b0 = *(const float4*)&brel[c8];
    float4 b1 = *(const float4*)&brel[c8+4];
    float bb[8] = {b0.x,b0.y,b0.z,b0.w,b1.x,b1.y,b1.z,b1.w};
    ushort8v o;
    #pragma unroll
    for (int j=0;j<8;j++) o[j] = f2b(a[j] + b2f(r8[j]) + bb[j]);
    *(ushort8v*)&hout[((size_t)node<<6) + c8] = o;
  }
}

// ---------------- pooling + final linear fused ----------------
__global__ __launch_bounds__(256) void k_pool(const ushort* __restrict__ h, const int* __restrict__ batch,
                       const float* __restrict__ Wlin, const float* __restrict__ blin,
                       float* __restrict__ out){
  int g = blockIdx.x;
  int lo=0, hi=NN;
  while (lo<hi){ int mid=(lo+hi)>>1; if (batch[mid] < g) lo=mid+1; else hi=mid; }
  int beg = lo;
  lo=0; hi=NN;
  while (lo<hi){ int mid=(lo+hi)>>1; if (batch[mid] < g+1) lo=mid+1; else hi=mid; }
  int end = lo;
  int lane = threadIdx.x & 63;
  int w = threadIdx.x >> 6;
  float acc = 0.f;
  for (int n = beg + w; n < end; n += 4) acc += b2f(h[(size_t)n*64 + lane]);
  __shared__ float red[4][64];
  __shared__ float p[64];
  red[w][lane] = acc;
  __syncthreads();
  if (w == 0){
    float v = red[0][lane]+red[1][lane]+red[2][lane]+red[3][lane];
    int cnt = end - beg;
    p[lane] = v / fmaxf((float)cnt, 1.f);
  }
  __syncthreads();
  if (w == 0){
    float o = blin[lane];
    #pragma unroll 8
    for (int k=0;k<64;k++) o += p[k]*Wlin[k*64+lane];
    out[g*64+lane] = o;
  }
}

extern "C" void kernel_launch(void* const* d_in, const int* in_sizes, int n_in,
                              void* d_out, int out_size, void* d_ws, size_t ws_size,
                              hipStream_t stream){
  const float* x     = (const float*)d_in[0];
  const int*   ei    = (const int*)  d_in[1];
  const int*   batch = (const int*)  d_in[2];
  const float* Wrel1 = (const float*)d_in[3];
  const float* brel1 = (const float*)d_in[4];
  const float* Wroot1= (const float*)d_in[5];
  const float* Wrel2 = (const float*)d_in[6];
  const float* brel2 = (const float*)d_in[7];
  const float* Wroot2= (const float*)d_in[8];
  const float* Wrel3 = (const float*)d_in[9];
  const float* brel3 = (const float*)d_in[10];
  const float* Wroot3= (const float*)d_in[11];
  const float* Wlin  = (const float*)d_in[12];
  const float* blin  = (const float*)d_in[13];
  const int* src = ei;
  const int* dst = ei + NE;

  char* wsB = (char*)d_ws;
  size_t off = 0;
  auto alloc = [&](size_t bytes)->void*{
    void* p = wsB + off; off = (off + bytes + 255) & ~(size_t)255; return p;
  };
  int*      csr    = (int*)     alloc((size_t)NBK*BCAP*4);    // 7.2 MB bucket-padded
  unsigned* ebuf   = (unsigned*)alloc((size_t)NBK*BCAP*4);    // 7.2 MB bucket-padded
  int*      rowptr = (int*)     alloc((size_t)NN*4);
  int*      degarr = (int*)     alloc((size_t)NN*4);
  int*      gcur   = (int*)     alloc(NBK*4);
  ushort*   wp     = (ushort*)  alloc((size_t)3*8192*2);      // 48 KB
  ushort*   Y      = (ushort*)  alloc((size_t)NN*64*2);       // 12.8 MB
  ushort*   R      = (ushort*)  alloc((size_t)NN*64*2);       // 12.8 MB
  ushort*   Y2     = (ushort*)  alloc((size_t)NN*64*2);       // 12.8 MB
  ushort*   R2     = (ushort*)  alloc((size_t)NN*64*2);       // 12.8 MB
  ushort*   h3     = (ushort*)  alloc((size_t)NN*64*2);       // 12.8 MB

  k_wpack3  <<<(3*8192+255)/256,256,0,stream>>>(Wrel1,Wroot1,Wrel2,Wroot2,Wrel3,Wroot3, wp, gcur);
  k_bscatter<<<NSB,256,0,stream>>>(src, dst, gcur, ebuf);
  k_bfill   <<<NBK,256,0,stream>>>(ebuf, gcur, rowptr, degarr, csr);

  int gb = (NN+63)/64;
  int ab = (NN+3)/4;

  // layer 1 GEMM (A = x, f32 cast fused)
  k_gemm_mfma<<<gb,256,0,stream>>>(x, wp + 0*8192, Y, R);
  // fused: aggr layer1 + gemm layer2
  k_fused   <<<FB,256,0,stream>>>(Y, R, brel1, rowptr, degarr, csr, wp + 1*8192, Y2, R2);
  // fused: aggr layer2 + gemm layer3
  k_fused   <<<FB,256,0,stream>>>(Y2, R2, brel2, rowptr, degarr, csr, wp + 2*8192, Y, R);
  // final aggr (layer3, no relu)
  k_aggr    <<<ab,256,0,stream>>>(Y, R, brel3, rowptr, degarr, csr, h3);

  k_pool <<<NG,256,0,stream>>>(h3, batch, Wlin, blin, (float*)d_out);
}

// Round 16
// 261.229 us; speedup vs baseline: 1.1435x; 1.1435x over previous
//
#include <hip/hip_runtime.h>
#include <hip/hip_bf16.h>

#define NN 100000
#define NE 1600000
#define DD 64
#define NG 256
#define SHIFT 8     // 256 nodes per bucket
#define NBK 391     // ceil(NN/256)
#define BCAP 4608   // bucket capacity: mean 4092, +8 sigma
#define NSB 1024    // scatter blocks (4 blocks/CU)
#define CHUNK 1563  // edges per scatter block (1024*1563 >= NE)

typedef __attribute__((ext_vector_type(8))) short bf16x8;
typedef __attribute__((ext_vector_type(4))) float f32x4;
typedef __attribute__((ext_vector_type(8))) unsigned short ushort8v;

__device__ __forceinline__ float b2f(ushort u){
  unsigned v = ((unsigned)u) << 16;
  return __uint_as_float(v);
}
__device__ __forceinline__ ushort f2b(float f){
  __hip_bfloat16 b = __float2bfloat16(f);
  return *(ushort*)&b;
}

// ---------------- weight packing + gcur init (fused) ----------------
// wp layout per layer: [s(2)][t(8)][lane(64)][j(8)] bf16
// value = W[k][col], k = s*32 + (lane>>4)*8 + j, col = t*16 + (lane&15)
__global__ void k_wpack3(const float* __restrict__ Wr1, const float* __restrict__ Wo1,
                         const float* __restrict__ Wr2, const float* __restrict__ Wo2,
                         const float* __restrict__ Wr3, const float* __restrict__ Wo3,
                         ushort* __restrict__ wp, int* __restrict__ gcur){
  int i = blockIdx.x*256 + threadIdx.x;
  if (i < NBK) gcur[i] = i*BCAP;          // fixed bucket bases
  if (i >= 3*8192) return;
  int lay = i >> 13;
  int r = i & 8191;
  int j = r & 7, l = (r>>3) & 63, t = (r>>9) & 7, s = r >> 12;
  int k = s*32 + ((l>>4)<<3) + j;
  int col = t*16 + (l&15);
  const float* Wrel  = (lay==0) ? Wr1 : (lay==1) ? Wr2 : Wr3;
  const float* Wroot = (lay==0) ? Wo1 : (lay==1) ? Wo2 : Wo3;
  float v = (col < 64) ? Wrel[k*64 + col] : Wroot[k*64 + (col-64)];
  wp[i] = f2b(v);
}

// ---------------- scatter: per-block hist -> reserve -> write packed edges ----------------
__global__ __launch_bounds__(256) void k_bscatter(const int* __restrict__ src, const int* __restrict__ dst,
                           int* __restrict__ gcur, unsigned* __restrict__ ebuf){
  __shared__ int h[NBK];
  __shared__ int base[NBK];
  __shared__ int lcur[NBK];
  for (int i=threadIdx.x; i<NBK; i+=256) h[i]=0;
  __syncthreads();
  const int e0 = blockIdx.x*CHUNK;
  const int e1 = min(e0+CHUNK, NE);
  for (int e=e0+threadIdx.x; e<e1; e+=256) atomicAdd(&h[dst[e]>>SHIFT], 1);
  __syncthreads();
  for (int i=threadIdx.x; i<NBK; i+=256){
    base[i] = h[i] ? atomicAdd(&gcur[i], h[i]) : 0;
    lcur[i] = 0;
  }
  __syncthreads();
  for (int e=e0+threadIdx.x; e<e1; e+=256){
    int d = dst[e];
    int b = d >> SHIFT;
    int r = atomicAdd(&lcur[b], 1);
    size_t idx = (size_t)base[b] + r;
    if (idx < (size_t)NBK*BCAP)
      ebuf[idx] = ((unsigned)(d & 255) << 17) | (unsigned)src[e];   // 8b local-dst | 17b src
  }
}

// ---------------- per-bucket LDS counting sort -> bucket-padded CSR + rowptr + deg ----------------
__global__ __launch_bounds__(512) void k_bfill(const unsigned* __restrict__ ebuf, const int* __restrict__ gcur,
                        int* __restrict__ rowptr, int* __restrict__ degarr, int* __restrict__ csr){
  __shared__ int c[256];
  __shared__ int lcur[256];
  __shared__ int s[256];
  __shared__ int scnt;
  const int b = blockIdx.x, t = threadIdx.x;
  const int ebase = b*BCAP;
  if (t == 0) scnt = min(gcur[b] - ebase, BCAP);
  if (t < 256) c[t] = 0;
  __syncthreads();
  const int cnt = scnt;
  for (int i=t; i<cnt; i+=512) atomicAdd(&c[ebuf[ebase+i]>>17], 1);
  __syncthreads();
  int v = (t < 256) ? c[t] : 0;
  if (t < 256) s[t] = v;
  __syncthreads();
  for (int off=1; off<256; off<<=1){
    int u = (t >= off && t < 256) ? s[t-off] : 0;
    __syncthreads();
    if (t < 256) s[t] += u;
    __syncthreads();
  }
  if (t < 256){
    int excl = s[t] - v;
    lcur[t] = excl;
    int node = (b << SHIFT) + t;
    if (node < NN){ rowptr[node] = ebase + excl; degarr[node] = v; }
  }
  __syncthreads();
  for (int i=t; i<cnt; i+=512){
    unsigned p = ebuf[ebase+i];
    int dl = (int)(p >> 17);
    int r = atomicAdd(&lcur[dl], 1);
    csr[ebase + r] = (int)(p & 0x1FFFFu);
  }
}

// ---------------- MFMA dual GEMM: [Y | R] = A @ [Wrel | Wroot] ----------------
// LDS-transpose epilogue: C tile staged in LDS, re-read as ushort8 -> coalesced 16B stores.
#define CPAD 136   // row pad (ushorts): 272B = 16B-aligned rows, bank-spread
__global__ __launch_bounds__(256) void k_gemm_mfma(const void* __restrict__ Av, int aIsF32,
    const ushort* __restrict__ wp, ushort* __restrict__ Y, ushort* __restrict__ Rr){
  __shared__ ushort ct[64*CPAD];   // 17408 B
  const int tid = threadIdx.x;
  const int w = tid >> 6, l = tid & 63;
  const int m = l & 15, kg = l >> 4;
  const int row0 = blockIdx.x*64;
  int arow = row0 + w*16 + m; if (arow >= NN) arow = NN-1;   // clamp; stores guarded
  bf16x8 a0, a1;
  if (aIsF32){
    const float* Af = (const float*)Av;
    float4 f0 = *(const float4*)&Af[(size_t)arow*64 + kg*8];
    float4 f1 = *(const float4*)&Af[(size_t)arow*64 + kg*8 + 4];
    float4 f2 = *(const float4*)&Af[(size_t)arow*64 + 32 + kg*8];
    float4 f3 = *(const float4*)&Af[(size_t)arow*64 + 32 + kg*8 + 4];
    a0[0]=(short)f2b(f0.x); a0[1]=(short)f2b(f0.y); a0[2]=(short)f2b(f0.z); a0[3]=(short)f2b(f0.w);
    a0[4]=(short)f2b(f1.x); a0[5]=(short)f2b(f1.y); a0[6]=(short)f2b(f1.z); a0[7]=(short)f2b(f1.w);
    a1[0]=(short)f2b(f2.x); a1[1]=(short)f2b(f2.y); a1[2]=(short)f2b(f2.z); a1[3]=(short)f2b(f2.w);
    a1[4]=(short)f2b(f3.x); a1[5]=(short)f2b(f3.y); a1[6]=(short)f2b(f3.z); a1[7]=(short)f2b(f3.w);
  } else {
    const ushort* Ab = (const ushort*)Av;
    a0 = *(const bf16x8*)&Ab[(size_t)arow*64 + kg*8];
    a1 = *(const bf16x8*)&Ab[(size_t)arow*64 + 32 + kg*8];
  }
  #pragma unroll
  for (int t=0; t<8; t++){
    bf16x8 b0 = *(const bf16x8*)&wp[((size_t)(0*8+t)*64 + l)*8];
    bf16x8 b1 = *(const bf16x8*)&wp[((size_t)(1*8+t)*64 + l)*8];
    f32x4 c = {0.f, 0.f, 0.f, 0.f};
    c = __builtin_amdgcn_mfma_f32_16x16x32_bf16(a0, b0, c, 0, 0, 0);
    c = __builtin_amdgcn_mfma_f32_16x16x32_bf16(a1, b1, c, 0, 0, 0);
    #pragma unroll
    for (int reg=0; reg<4; reg++){
      int lrow = w*16 + kg*4 + reg;     // D: row=(lane>>4)*4+reg, col=lane&15
      ct[lrow*CPAD + t*16 + m] = f2b(c[reg]);
    }
  }
  __syncthreads();
  // cooperative coalesced store: 64 rows x 16 col-blocks of 8 ushorts
  #pragma unroll
  for (int u=0; u<4; u++){
    int i = tid + u*256;               // 0..1023
    int lrow = i >> 4, cb = i & 15;
    int grow = row0 + lrow;
    if (grow < NN){
      ushort8v v = *(const ushort8v*)&ct[lrow*CPAD + cb*8];
      if (cb < 8) *(ushort8v*)&Y [(size_t)grow*64 + cb*8]       = v;
      else        *(ushort8v*)&Rr[(size_t)grow*64 + (cb-8)*8]   = v;
    }
  }
}

// ---------------- gather-aggregate: 8 lanes/edge (ushort8), 16 edges in flight ----------------
__global__ __launch_bounds__(256) void k_aggr(const ushort* __restrict__ Y,
    const ushort* __restrict__ R, const float* __restrict__ brel,
    const int* __restrict__ rowptr, const int* __restrict__ degarr, const int* __restrict__ csr,
    ushort* __restrict__ hout, int do_relu){
  int node = blockIdx.x*4 + (threadIdx.x>>6);
  if (node >= NN) return;
  int lane = threadIdx.x & 63;
  int g = lane >> 3;
  int c8 = (lane & 7) << 3;
  int beg = rowptr[node];
  int dc = degarr[node];
  const int* lst = csr + beg;
  float a[8] = {0.f,0.f,0.f,0.f,0.f,0.f,0.f,0.f};
  int i = g;
  for (; i + 8 < dc; i += 16){          // pair: 16 edges in flight per wave
    int s0 = lst[i], s1 = lst[i+8];
    ushort8v y0 = *(const ushort8v*)&Y[((size_t)s0<<6) + c8];
    ushort8v y1 = *(const ushort8v*)&Y[((size_t)s1<<6) + c8];
    #pragma unroll
    for (int j=0;j<8;j++) a[j] += b2f(y0[j]) + b2f(y1[j]);
  }
  if (i < dc){
    int s0 = lst[i];
    ushort8v y0 = *(const ushort8v*)&Y[((size_t)s0<<6) + c8];
    #pragma unroll
    for (int j=0;j<8;j++) a[j] += b2f(y0[j]);
  }
  #pragma unroll
  for (int j=0;j<8;j++){
    a[j] += __shfl_xor(a[j], 8);
    a[j] += __shfl_xor(a[j], 16);
    a[j] += __shfl_xor(a[j], 32);
  }
  if (g == 0){
    ushort8v r8 = *(const ushort8v*)&R[((size_t)node<<6) + c8];
    float4 b0 = *(const float4*)&brel[c8];
    float4 b1 = *(const float4*)&brel[c8+4];
    float bb[8] = {b0.x,b0.y,b0.z,b0.w,b1.x,b1.y,b1.z,b1.w};
    ushort8v o;
    #pragma unroll
    for (int j=0;j<8;j++){
      float v = a[j] + b2f(r8[j]) + bb[j];
      if (do_relu) v = fmaxf(v, 0.f);
      o[j] = f2b(v);
    }
    *(ushort8v*)&hout[((size_t)node<<6) + c8] = o;
  }
}

// ---------------- pooling + final linear fused ----------------
__global__ __launch_bounds__(256) void k_pool(const ushort* __restrict__ h, const int* __restrict__ batch,
                       const float* __restrict__ Wlin, const float* __restrict__ blin,
                       float* __restrict__ out){
  int g = blockIdx.x;
  int lo=0, hi=NN;
  while (lo<hi){ int mid=(lo+hi)>>1; if (batch[mid] < g) lo=mid+1; else hi=mid; }
  int beg = lo;
  lo=0; hi=NN;
  while (lo<hi){ int mid=(lo+hi)>>1; if (batch[mid] < g+1) lo=mid+1; else hi=mid; }
  int end = lo;
  int lane = threadIdx.x & 63;
  int w = threadIdx.x >> 6;
  float acc = 0.f;
  for (int n = beg + w; n < end; n += 4) acc += b2f(h[(size_t)n*64 + lane]);
  __shared__ float red[4][64];
  __shared__ float p[64];
  red[w][lane] = acc;
  __syncthreads();
  if (w == 0){
    float v = red[0][lane]+red[1][lane]+red[2][lane]+red[3][lane];
    int cnt = end - beg;
    p[lane] = v / fmaxf((float)cnt, 1.f);
  }
  __syncthreads();
  if (w == 0){
    float o = blin[lane];
    #pragma unroll 8
    for (int k=0;k<64;k++) o += p[k]*Wlin[k*64+lane];
    out[g*64+lane] = o;
  }
}

extern "C" void kernel_launch(void* const* d_in, const int* in_sizes, int n_in,
                              void* d_out, int out_size, void* d_ws, size_t ws_size,
                              hipStream_t stream){
  const float* x     = (const float*)d_in[0];
  const int*   ei    = (const int*)  d_in[1];
  const int*   batch = (const int*)  d_in[2];
  const float* Wrel1 = (const float*)d_in[3];
  const float* brel1 = (const float*)d_in[4];
  const float* Wroot1= (const float*)d_in[5];
  const float* Wrel2 = (const float*)d_in[6];
  const float* brel2 = (const float*)d_in[7];
  const float* Wroot2= (const float*)d_in[8];
  const float* Wrel3 = (const float*)d_in[9];
  const float* brel3 = (const float*)d_in[10];
  const float* Wroot3= (const float*)d_in[11];
  const float* Wlin  = (const float*)d_in[12];
  const float* blin  = (const float*)d_in[13];
  const int* src = ei;
  const int* dst = ei + NE;

  char* wsB = (char*)d_ws;
  size_t off = 0;
  auto alloc = [&](size_t bytes)->void*{
    void* p = wsB + off; off = (off + bytes + 255) & ~(size_t)255; return p;
  };
  int*      csr    = (int*)     alloc((size_t)NBK*BCAP*4);    // 7.2 MB bucket-padded
  unsigned* ebuf   = (unsigned*)alloc((size_t)NBK*BCAP*4);    // 7.2 MB bucket-padded
  int*      rowptr = (int*)     alloc((size_t)NN*4);
  int*      degarr = (int*)     alloc((size_t)NN*4);
  int*      gcur   = (int*)     alloc(NBK*4);
  ushort*   wp     = (ushort*)  alloc((size_t)3*8192*2);      // 48 KB
  ushort*   Y      = (ushort*)  alloc((size_t)NN*64*2);       // 12.8 MB
  ushort*   R      = (ushort*)  alloc((size_t)NN*64*2);       // 12.8 MB
  ushort*   h1     = (ushort*)  alloc((size_t)NN*64*2);       // 12.8 MB
  ushort*   h2     = (ushort*)  alloc((size_t)NN*64*2);       // 12.8 MB

  k_wpack3  <<<(3*8192+255)/256,256,0,stream>>>(Wrel1,Wroot1,Wrel2,Wroot2,Wrel3,Wroot3, wp, gcur);
  k_bscatter<<<NSB,256,0,stream>>>(src, dst, gcur, ebuf);
  k_bfill   <<<NBK,512,0,stream>>>(ebuf, gcur, rowptr, degarr, csr);

  int gb = (NN+63)/64;
  int ab = (NN+3)/4;

  // layer 1 (A = x, f32, cast fused into GEMM)
  k_gemm_mfma<<<gb,256,0,stream>>>(x,  1, wp + 0*8192, Y, R);
  k_aggr     <<<ab,256,0,stream>>>(Y, R, brel1, rowptr, degarr, csr, h1, 1);
  // layer 2
  k_gemm_mfma<<<gb,256,0,stream>>>(h1, 0, wp + 1*8192, Y, R);
  k_aggr     <<<ab,256,0,stream>>>(Y, R, brel2, rowptr, degarr, csr, h2, 1);
  // layer 3 (no relu)
  k_gemm_mfma<<<gb,256,0,stream>>>(h2, 0, wp + 2*8192, Y, R);
  k_aggr     <<<ab,256,0,stream>>>(Y, R, brel3, rowptr, degarr, csr, h1, 0);

  k_pool <<<NG,256,0,stream>>>(h1, batch, Wlin, blin, (float*)d_out);
}

// Round 17
// 241.679 us; speedup vs baseline: 1.2360x; 1.0809x over previous
//
#include <hip/hip_runtime.h>
#include <hip/hip_bf16.h>

#define NN 100000
#define NE 1600000
#define DD 64
#define NG 256
#define SHIFT 8     // 256 nodes per bucket
#define NBK 391     // ceil(NN/256)
#define BCAP 4608   // bucket capacity: mean 4092, +8 sigma
#define NSB 256     // scatter blocks (long runs -> coherent writes)
#define CHUNK 6250  // edges per scatter block

typedef __attribute__((ext_vector_type(8))) short bf16x8;
typedef __attribute__((ext_vector_type(4))) float f32x4;
typedef __attribute__((ext_vector_type(8))) unsigned short ushort8v;

__device__ __forceinline__ float b2f(ushort u){
  unsigned v = ((unsigned)u) << 16;
  return __uint_as_float(v);
}
__device__ __forceinline__ ushort f2b(float f){
  __hip_bfloat16 b = __float2bfloat16(f);
  return *(ushort*)&b;
}

// ---------------- weight packing + gcur init (fused) ----------------
// wp layout per layer: [s(2)][t(8)][lane(64)][j(8)] bf16
// value = W[k][col], k = s*32 + (lane>>4)*8 + j, col = t*16 + (lane&15)
__global__ void k_wpack3(const float* __restrict__ Wr1, const float* __restrict__ Wo1,
                         const float* __restrict__ Wr2, const float* __restrict__ Wo2,
                         const float* __restrict__ Wr3, const float* __restrict__ Wo3,
                         ushort* __restrict__ wp, int* __restrict__ gcur){
  int i = blockIdx.x*256 + threadIdx.x;
  if (i < NBK) gcur[i] = i*BCAP;          // fixed bucket bases
  if (i >= 3*8192) return;
  int lay = i >> 13;
  int r = i & 8191;
  int j = r & 7, l = (r>>3) & 63, t = (r>>9) & 7, s = r >> 12;
  int k = s*32 + ((l>>4)<<3) + j;
  int col = t*16 + (l&15);
  const float* Wrel  = (lay==0) ? Wr1 : (lay==1) ? Wr2 : Wr3;
  const float* Wroot = (lay==0) ? Wo1 : (lay==1) ? Wo2 : Wo3;
  float v = (col < 64) ? Wrel[k*64 + col] : Wroot[k*64 + (col-64)];
  wp[i] = f2b(v);
}

// ---------------- scatter: per-block hist -> reserve -> write packed edges ----------------
// 512 threads (8 waves) per block: more TLP on the dependent load->atomic->scatter chain,
// same per-block run lengths (write coherence preserved).
__global__ __launch_bounds__(512) void k_bscatter(const int* __restrict__ src, const int* __restrict__ dst,
                           int* __restrict__ gcur, unsigned* __restrict__ ebuf){
  __shared__ int h[NBK];
  __shared__ int base[NBK];
  __shared__ int lcur[NBK];
  for (int i=threadIdx.x; i<NBK; i+=512) h[i]=0;
  __syncthreads();
  const int e0 = blockIdx.x*CHUNK;
  const int e1 = min(e0+CHUNK, NE);
  for (int e=e0+threadIdx.x; e<e1; e+=512) atomicAdd(&h[dst[e]>>SHIFT], 1);
  __syncthreads();
  for (int i=threadIdx.x; i<NBK; i+=512){
    base[i] = h[i] ? atomicAdd(&gcur[i], h[i]) : 0;
    lcur[i] = 0;
  }
  __syncthreads();
  for (int e=e0+threadIdx.x; e<e1; e+=512){
    int d = dst[e];
    int b = d >> SHIFT;
    int r = atomicAdd(&lcur[b], 1);
    size_t idx = (size_t)base[b] + r;
    if (idx < (size_t)NBK*BCAP)
      ebuf[idx] = ((unsigned)(d & 255) << 17) | (unsigned)src[e];   // 8b local-dst | 17b src
  }
}

// ---------------- per-bucket LDS counting sort -> bucket-padded CSR + rowptr + deg ----------------
__global__ __launch_bounds__(512) void k_bfill(const unsigned* __restrict__ ebuf, const int* __restrict__ gcur,
                        int* __restrict__ rowptr, int* __restrict__ degarr, int* __restrict__ csr){
  __shared__ int c[256];
  __shared__ int lcur[256];
  __shared__ int s[256];
  __shared__ int scnt;
  const int b = blockIdx.x, t = threadIdx.x;
  const int ebase = b*BCAP;
  if (t == 0) scnt = min(gcur[b] - ebase, BCAP);
  if (t < 256) c[t] = 0;
  __syncthreads();
  const int cnt = scnt;
  for (int i=t; i<cnt; i+=512) atomicAdd(&c[ebuf[ebase+i]>>17], 1);
  __syncthreads();
  int v = (t < 256) ? c[t] : 0;
  if (t < 256) s[t] = v;
  __syncthreads();
  for (int off=1; off<256; off<<=1){
    int u = (t >= off && t < 256) ? s[t-off] : 0;
    __syncthreads();
    if (t < 256) s[t] += u;
    __syncthreads();
  }
  if (t < 256){
    int excl = s[t] - v;
    lcur[t] = excl;
    int node = (b << SHIFT) + t;
    if (node < NN){ rowptr[node] = ebase + excl; degarr[node] = v; }
  }
  __syncthreads();
  for (int i=t; i<cnt; i+=512){
    unsigned p = ebuf[ebase+i];
    int dl = (int)(p >> 17);
    int r = atomicAdd(&lcur[dl], 1);
    csr[ebase + r] = (int)(p & 0x1FFFFu);
  }
}

// ---------------- MFMA dual GEMM: [Y | R] = A @ [Wrel | Wroot] ----------------
// LDS-transpose epilogue: C tile staged in LDS, re-read as ushort8 -> coalesced 16B stores.
#define CPAD 136   // row pad (ushorts): 272B = 16B-aligned rows, bank-spread
__global__ __launch_bounds__(256) void k_gemm_mfma(const void* __restrict__ Av, int aIsF32,
    const ushort* __restrict__ wp, ushort* __restrict__ Y, ushort* __restrict__ Rr){
  __shared__ ushort ct[64*CPAD];   // 17408 B
  const int tid = threadIdx.x;
  const int w = tid >> 6, l = tid & 63;
  const int m = l & 15, kg = l >> 4;
  const int row0 = blockIdx.x*64;
  int arow = row0 + w*16 + m; if (arow >= NN) arow = NN-1;   // clamp; stores guarded
  bf16x8 a0, a1;
  if (aIsF32){
    const float* Af = (const float*)Av;
    float4 f0 = *(const float4*)&Af[(size_t)arow*64 + kg*8];
    float4 f1 = *(const float4*)&Af[(size_t)arow*64 + kg*8 + 4];
    float4 f2 = *(const float4*)&Af[(size_t)arow*64 + 32 + kg*8];
    float4 f3 = *(const float4*)&Af[(size_t)arow*64 + 32 + kg*8 + 4];
    a0[0]=(short)f2b(f0.x); a0[1]=(short)f2b(f0.y); a0[2]=(short)f2b(f0.z); a0[3]=(short)f2b(f0.w);
    a0[4]=(short)f2b(f1.x); a0[5]=(short)f2b(f1.y); a0[6]=(short)f2b(f1.z); a0[7]=(short)f2b(f1.w);
    a1[0]=(short)f2b(f2.x); a1[1]=(short)f2b(f2.y); a1[2]=(short)f2b(f2.z); a1[3]=(short)f2b(f2.w);
    a1[4]=(short)f2b(f3.x); a1[5]=(short)f2b(f3.y); a1[6]=(short)f2b(f3.z); a1[7]=(short)f2b(f3.w);
  } else {
    const ushort* Ab = (const ushort*)Av;
    a0 = *(const bf16x8*)&Ab[(size_t)arow*64 + kg*8];
    a1 = *(const bf16x8*)&Ab[(size_t)arow*64 + 32 + kg*8];
  }
  #pragma unroll
  for (int t=0; t<8; t++){
    bf16x8 b0 = *(const bf16x8*)&wp[((size_t)(0*8+t)*64 + l)*8];
    bf16x8 b1 = *(const bf16x8*)&wp[((size_t)(1*8+t)*64 + l)*8];
    f32x4 c = {0.f, 0.f, 0.f, 0.f};
    c = __builtin_amdgcn_mfma_f32_16x16x32_bf16(a0, b0, c, 0, 0, 0);
    c = __builtin_amdgcn_mfma_f32_16x16x32_bf16(a1, b1, c, 0, 0, 0);
    #pragma unroll
    for (int reg=0; reg<4; reg++){
      int lrow = w*16 + kg*4 + reg;     // D: row=(lane>>4)*4+reg, col=lane&15
      ct[lrow*CPAD + t*16 + m] = f2b(c[reg]);
    }
  }
  __syncthreads();
  // cooperative coalesced store: 64 rows x 16 col-blocks of 8 ushorts
  #pragma unroll
  for (int u=0; u<4; u++){
    int i = tid + u*256;               // 0..1023
    int lrow = i >> 4, cb = i & 15;
    int grow = row0 + lrow;
    if (grow < NN){
      ushort8v v = *(const ushort8v*)&ct[lrow*CPAD + cb*8];
      if (cb < 8) *(ushort8v*)&Y [(size_t)grow*64 + cb*8]       = v;
      else        *(ushort8v*)&Rr[(size_t)grow*64 + (cb-8)*8]   = v;
    }
  }
}

// ---------------- gather-aggregate: 8 lanes/edge (ushort8), 16 edges in flight ----------------
__global__ __launch_bounds__(256) void k_aggr(const ushort* __restrict__ Y,
    const ushort* __restrict__ R, const float* __restrict__ brel,
    const int* __restrict__ rowptr, const int* __restrict__ degarr, const int* __restrict__ csr,
    ushort* __restrict__ hout, int do_relu){
  int node = blockIdx.x*4 + (threadIdx.x>>6);
  if (node >= NN) return;
  int lane = threadIdx.x & 63;
  int g = lane >> 3;
  int c8 = (lane & 7) << 3;
  int beg = rowptr[node];
  int dc = degarr[node];
  const int* lst = csr + beg;
  float a[8] = {0.f,0.f,0.f,0.f,0.f,0.f,0.f,0.f};
  int i = g;
  for (; i + 8 < dc; i += 16){          // pair: 16 edges in flight per wave
    int s0 = lst[i], s1 = lst[i+8];
    ushort8v y0 = *(const ushort8v*)&Y[((size_t)s0<<6) + c8];
    ushort8v y1 = *(const ushort8v*)&Y[((size_t)s1<<6) + c8];
    #pragma unroll
    for (int j=0;j<8;j++) a[j] += b2f(y0[j]) + b2f(y1[j]);
  }
  if (i < dc){
    int s0 = lst[i];
    ushort8v y0 = *(const ushort8v*)&Y[((size_t)s0<<6) + c8];
    #pragma unroll
    for (int j=0;j<8;j++) a[j] += b2f(y0[j]);
  }
  #pragma unroll
  for (int j=0;j<8;j++){
    a[j] += __shfl_xor(a[j], 8);
    a[j] += __shfl_xor(a[j], 16);
    a[j] += __shfl_xor(a[j], 32);
  }
  if (g == 0){
    ushort8v r8 = *(const ushort8v*)&R[((size_t)node<<6) + c8];
    float4 b0 = *(const float4*)&brel[c8];
    float4 b1 = *(const float4*)&brel[c8+4];
    float bb[8] = {b0.x,b0.y,b0.z,b0.w,b1.x,b1.y,b1.z,b1.w};
    ushort8v o;
    #pragma unroll
    for (int j=0;j<8;j++){
      float v = a[j] + b2f(r8[j]) + bb[j];
      if (do_relu) v = fmaxf(v, 0.f);
      o[j] = f2b(v);
    }
    *(ushort8v*)&hout[((size_t)node<<6) + c8] = o;
  }
}

// ---------------- pooling + final linear fused ----------------
__global__ __launch_bounds__(256) void k_pool(const ushort* __restrict__ h, const int* __restrict__ batch,
                       const float* __restrict__ Wlin, const float* __restrict__ blin,
                       float* __restrict__ out){
  int g = blockIdx.x;
  int lo=0, hi=NN;
  while (lo<hi){ int mid=(lo+hi)>>1; if (batch[mid] < g) lo=mid+1; else hi=mid; }
  int beg = lo;
  lo=0; hi=NN;
  while (lo<hi){ int mid=(lo+hi)>>1; if (batch[mid] < g+1) lo=mid+1; else hi=mid; }
  int end = lo;
  int lane = threadIdx.x & 63;
  int w = threadIdx.x >> 6;
  float acc = 0.f;
  for (int n = beg + w; n < end; n += 4) acc += b2f(h[(size_t)n*64 + lane]);
  __shared__ float red[4][64];
  __shared__ float p[64];
  red[w][lane] = acc;
  __syncthreads();
  if (w == 0){
    float v = red[0][lane]+red[1][lane]+red[2][lane]+red[3][lane];
    int cnt = end - beg;
    p[lane] = v / fmaxf((float)cnt, 1.f);
  }
  __syncthreads();
  if (w == 0){
    float o = blin[lane];
    #pragma unroll 8
    for (int k=0;k<64;k++) o += p[k]*Wlin[k*64+lane];
    out[g*64+lane] = o;
  }
}

extern "C" void kernel_launch(void* const* d_in, const int* in_sizes, int n_in,
                              void* d_out, int out_size, void* d_ws, size_t ws_size,
                              hipStream_t stream){
  const float* x     = (const float*)d_in[0];
  const int*   ei    = (const int*)  d_in[1];
  const int*   batch = (const int*)  d_in[2];
  const float* Wrel1 = (const float*)d_in[3];
  const float* brel1 = (const float*)d_in[4];
  const float* Wroot1= (const float*)d_in[5];
  const float* Wrel2 = (const float*)d_in[6];
  const float* brel2 = (const float*)d_in[7];
  const float* Wroot2= (const float*)d_in[8];
  const float* Wrel3 = (const float*)d_in[9];
  const float* brel3 = (const float*)d_in[10];
  const float* Wroot3= (const float*)d_in[11];
  const float* Wlin  = (const float*)d_in[12];
  const float* blin  = (const float*)d_in[13];
  const int* src = ei;
  const int* dst = ei + NE;

  char* wsB = (char*)d_ws;
  size_t off = 0;
  auto alloc = [&](size_t bytes)->void*{
    void* p = wsB + off; off = (off + bytes + 255) & ~(size_t)255; return p;
  };
  int*      csr    = (int*)     alloc((size_t)NBK*BCAP*4);    // 7.2 MB bucket-padded
  unsigned* ebuf   = (unsigned*)alloc((size_t)NBK*BCAP*4);    // 7.2 MB bucket-padded
  int*      rowptr = (int*)     alloc((size_t)NN*4);
  int*      degarr = (int*)     alloc((size_t)NN*4);
  int*      gcur   = (int*)     alloc(NBK*4);
  ushort*   wp     = (ushort*)  alloc((size_t)3*8192*2);      // 48 KB
  ushort*   Y      = (ushort*)  alloc((size_t)NN*64*2);       // 12.8 MB
  ushort*   R      = (ushort*)  alloc((size_t)NN*64*2);       // 12.8 MB
  ushort*   h1     = (ushort*)  alloc((size_t)NN*64*2);       // 12.8 MB
  ushort*   h2     = (ushort*)  alloc((size_t)NN*64*2);       // 12.8 MB

  k_wpack3  <<<(3*8192+255)/256,256,0,stream>>>(Wrel1,Wroot1,Wrel2,Wroot2,Wrel3,Wroot3, wp, gcur);
  k_bscatter<<<NSB,512,0,stream>>>(src, dst, gcur, ebuf);
  k_bfill   <<<NBK,512,0,stream>>>(ebuf, gcur, rowptr, degarr, csr);

  int gb = (NN+63)/64;
  int ab = (NN+3)/4;

  // layer 1 (A = x, f32, cast fused into GEMM)
  k_gemm_mfma<<<gb,256,0,stream>>>(x,  1, wp + 0*8192, Y, R);
  k_aggr     <<<ab,256,0,stream>>>(Y, R, brel1, rowptr, degarr, csr, h1, 1);
  // layer 2
  k_gemm_mfma<<<gb,256,0,stream>>>(h1, 0, wp + 1*8192, Y, R);
  k_aggr     <<<ab,256,0,stream>>>(Y, R, brel2, rowptr, degarr, csr, h2, 1);
  // layer 3 (no relu)
  k_gemm_mfma<<<gb,256,0,stream>>>(h2, 0, wp + 2*8192, Y, R);
  k_aggr     <<<ab,256,0,stream>>>(Y, R, brel3, rowptr, degarr, csr, h1, 0);

  k_pool <<<NG,256,0,stream>>>(h1, batch, Wlin, blin, (float*)d_out);
}

// Round 18
// 237.393 us; speedup vs baseline: 1.2583x; 1.0181x over previous
//
#include <hip/hip_runtime.h>
#include <hip/hip_bf16.h>

#define NN 100000
#define NE 1600000
#define DD 64
#define NG 256
#define SHIFT 8     // 256 nodes per bucket
#define NBK 391     // ceil(NN/256)
#define BCAP 4608   // bucket capacity: mean 4092, +8 sigma
#define NSB 256     // scatter blocks (long runs -> coherent writes)
#define CHUNK 6250  // edges per scatter block
#define G1T 782     // layer-1 gemm tiles of 128 rows: ceil(NN/128)

typedef __attribute__((ext_vector_type(8))) short bf16x8;
typedef __attribute__((ext_vector_type(4))) float f32x4;
typedef __attribute__((ext_vector_type(8))) unsigned short ushort8v;

__device__ __forceinline__ float b2f(ushort u){
  unsigned v = ((unsigned)u) << 16;
  return __uint_as_float(v);
}
__device__ __forceinline__ ushort f2b(float f){
  __hip_bfloat16 b = __float2bfloat16(f);
  return *(ushort*)&b;
}

// ================= kernel 1: bscatter (blocks 0..255) + wpack (blocks 256..304) =================
// gcur pre-zeroed by memset; scatter base = b*BCAP + atomicAdd(gcur[b], h).
__global__ __launch_bounds__(512) void k_build1(const int* __restrict__ src, const int* __restrict__ dst,
                         int* __restrict__ gcur, unsigned* __restrict__ ebuf,
                         const float* __restrict__ Wr1, const float* __restrict__ Wo1,
                         const float* __restrict__ Wr2, const float* __restrict__ Wo2,
                         const float* __restrict__ Wr3, const float* __restrict__ Wo3,
                         ushort* __restrict__ wp){
  if (blockIdx.x >= NSB){
    int i = (blockIdx.x - NSB)*512 + threadIdx.x;
    if (i < 3*8192){
      int lay = i >> 13;
      int r = i & 8191;
      int j = r & 7, l = (r>>3) & 63, t = (r>>9) & 7, s = r >> 12;
      int k = s*32 + ((l>>4)<<3) + j;
      int col = t*16 + (l&15);
      const float* Wrel  = (lay==0) ? Wr1 : (lay==1) ? Wr2 : Wr3;
      const float* Wroot = (lay==0) ? Wo1 : (lay==1) ? Wo2 : Wo3;
      float v = (col < 64) ? Wrel[k*64 + col] : Wroot[k*64 + (col-64)];
      wp[i] = f2b(v);
    }
    return;
  }
  __shared__ int h[NBK];
  __shared__ int base[NBK];
  __shared__ int lcur[NBK];
  for (int i=threadIdx.x; i<NBK; i+=512) h[i]=0;
  __syncthreads();
  const int e0 = blockIdx.x*CHUNK;
  const int e1 = min(e0+CHUNK, NE);
  for (int e=e0+threadIdx.x; e<e1; e+=512) atomicAdd(&h[dst[e]>>SHIFT], 1);
  __syncthreads();
  for (int i=threadIdx.x; i<NBK; i+=512){
    base[i] = h[i] ? (i*BCAP + atomicAdd(&gcur[i], h[i])) : 0;
    lcur[i] = 0;
  }
  __syncthreads();
  for (int e=e0+threadIdx.x; e<e1; e+=512){
    int d = dst[e];
    int b = d >> SHIFT;
    int r = atomicAdd(&lcur[b], 1);
    size_t idx = (size_t)base[b] + r;
    if (idx < (size_t)NBK*BCAP)
      ebuf[idx] = ((unsigned)(d & 255) << 17) | (unsigned)src[e];   // 8b local-dst | 17b src
  }
}

// ================= kernel 2: bfill (blocks 0..390) + gemm layer1 (blocks 391..) =================
#define CPAD 136   // ct row pad (ushorts): 272B
union BG {
  struct { int c[256]; int lcur[256]; int s[256]; int scnt; } bf;
  ushort ct[128*CPAD];   // 34816 B
};
__global__ __launch_bounds__(512) void k_build2_gemm1(
    const unsigned* __restrict__ ebuf, const int* __restrict__ gcur,
    int* __restrict__ rowptr, int* __restrict__ degarr, int* __restrict__ csr,
    const float* __restrict__ Af, const ushort* __restrict__ wp,
    ushort* __restrict__ Y, ushort* __restrict__ Rr){
  __shared__ BG sm;
  const int t = threadIdx.x;
  if (blockIdx.x < NBK){
    // ---- bfill ----
    const int b = blockIdx.x;
    const int ebase = b*BCAP;
    if (t == 0) sm.bf.scnt = min(gcur[b], BCAP);
    if (t < 256) sm.bf.c[t] = 0;
    __syncthreads();
    const int cnt = sm.bf.scnt;
    for (int i=t; i<cnt; i+=512) atomicAdd(&sm.bf.c[ebuf[ebase+i]>>17], 1);
    __syncthreads();
    int v = (t < 256) ? sm.bf.c[t] : 0;
    if (t < 256) sm.bf.s[t] = v;
    __syncthreads();
    for (int off=1; off<256; off<<=1){
      int u = (t >= off && t < 256) ? sm.bf.s[t-off] : 0;
      __syncthreads();
      if (t < 256) sm.bf.s[t] += u;
      __syncthreads();
    }
    if (t < 256){
      int excl = sm.bf.s[t] - v;
      sm.bf.lcur[t] = excl;
      int node = (b << SHIFT) + t;
      if (node < NN){ rowptr[node] = ebase + excl; degarr[node] = v; }
    }
    __syncthreads();
    for (int i=t; i<cnt; i+=512){
      unsigned p = ebuf[ebase+i];
      int dl = (int)(p >> 17);
      int r = atomicAdd(&sm.bf.lcur[dl], 1);
      csr[ebase + r] = (int)(p & 0x1FFFFu);
    }
    return;
  }
  // ---- gemm layer 1 (f32 A), 128 rows per block, 8 waves ----
  const int tile = blockIdx.x - NBK;
  if (tile >= G1T) return;
  const int w = t >> 6, l = t & 63;
  const int m = l & 15, kg = l >> 4;
  const int row0 = tile*128;
  int arow = row0 + w*16 + m; if (arow >= NN) arow = NN-1;   // clamp; stores guarded
  bf16x8 a0, a1;
  {
    float4 f0 = *(const float4*)&Af[(size_t)arow*64 + kg*8];
    float4 f1 = *(const float4*)&Af[(size_t)arow*64 + kg*8 + 4];
    float4 f2 = *(const float4*)&Af[(size_t)arow*64 + 32 + kg*8];
    float4 f3 = *(const float4*)&Af[(size_t)arow*64 + 32 + kg*8 + 4];
    a0[0]=(short)f2b(f0.x); a0[1]=(short)f2b(f0.y); a0[2]=(short)f2b(f0.z); a0[3]=(short)f2b(f0.w);
    a0[4]=(short)f2b(f1.x); a0[5]=(short)f2b(f1.y); a0[6]=(short)f2b(f1.z); a0[7]=(short)f2b(f1.w);
    a1[0]=(short)f2b(f2.x); a1[1]=(short)f2b(f2.y); a1[2]=(short)f2b(f2.z); a1[3]=(short)f2b(f2.w);
    a1[4]=(short)f2b(f3.x); a1[5]=(short)f2b(f3.y); a1[6]=(short)f2b(f3.z); a1[7]=(short)f2b(f3.w);
  }
  #pragma unroll
  for (int tt=0; tt<8; tt++){
    bf16x8 b0 = *(const bf16x8*)&wp[((size_t)(0*8+tt)*64 + l)*8];
    bf16x8 b1 = *(const bf16x8*)&wp[((size_t)(1*8+tt)*64 + l)*8];
    f32x4 c = {0.f, 0.f, 0.f, 0.f};
    c = __builtin_amdgcn_mfma_f32_16x16x32_bf16(a0, b0, c, 0, 0, 0);
    c = __builtin_amdgcn_mfma_f32_16x16x32_bf16(a1, b1, c, 0, 0, 0);
    #pragma unroll
    for (int reg=0; reg<4; reg++){
      int lrow = w*16 + kg*4 + reg;
      sm.ct[lrow*CPAD + tt*16 + m] = f2b(c[reg]);
    }
  }
  __syncthreads();
  #pragma unroll
  for (int u=0; u<4; u++){
    int i = t + u*512;                 // 0..2047
    int lrow = i >> 4, cb = i & 15;
    int grow = row0 + lrow;
    if (grow < NN){
      ushort8v v = *(const ushort8v*)&sm.ct[lrow*CPAD + cb*8];
      if (cb < 8) *(ushort8v*)&Y [(size_t)grow*64 + cb*8]       = v;
      else        *(ushort8v*)&Rr[(size_t)grow*64 + (cb-8)*8]   = v;
    }
  }
}

// ================= MFMA dual GEMM (layers 2,3): bf16 A, 64 rows, 256 thr =================
__global__ __launch_bounds__(256) void k_gemm_mfma(const ushort* __restrict__ Ab,
    const ushort* __restrict__ wp, ushort* __restrict__ Y, ushort* __restrict__ Rr){
  __shared__ ushort ct[64*CPAD];   // 17408 B
  const int tid = threadIdx.x;
  const int w = tid >> 6, l = tid & 63;
  const int m = l & 15, kg = l >> 4;
  const int row0 = blockIdx.x*64;
  int arow = row0 + w*16 + m; if (arow >= NN) arow = NN-1;   // clamp; stores guarded
  bf16x8 a0 = *(const bf16x8*)&Ab[(size_t)arow*64 + kg*8];
  bf16x8 a1 = *(const bf16x8*)&Ab[(size_t)arow*64 + 32 + kg*8];
  #pragma unroll
  for (int t=0; t<8; t++){
    bf16x8 b0 = *(const bf16x8*)&wp[((size_t)(0*8+t)*64 + l)*8];
    bf16x8 b1 = *(const bf16x8*)&wp[((size_t)(1*8+t)*64 + l)*8];
    f32x4 c = {0.f, 0.f, 0.f, 0.f};
    c = __builtin_amdgcn_mfma_f32_16x16x32_bf16(a0, b0, c, 0, 0, 0);
    c = __builtin_amdgcn_mfma_f32_16x16x32_bf16(a1, b1, c, 0, 0, 0);
    #pragma unroll
    for (int reg=0; reg<4; reg++){
      int lrow = w*16 + kg*4 + reg;     // D: row=(lane>>4)*4+reg, col=lane&15
      ct[lrow*CPAD + t*16 + m] = f2b(c[reg]);
    }
  }
  __syncthreads();
  #pragma unroll
  for (int u=0; u<4; u++){
    int i = tid + u*256;               // 0..1023
    int lrow = i >> 4, cb = i & 15;
    int grow = row0 + lrow;
    if (grow < NN){
      ushort8v v = *(const ushort8v*)&ct[lrow*CPAD + cb*8];
      if (cb < 8) *(ushort8v*)&Y [(size_t)grow*64 + cb*8]       = v;
      else        *(ushort8v*)&Rr[(size_t)grow*64 + (cb-8)*8]   = v;
    }
  }
}

// ================= gather-aggregate: 8 lanes/edge (ushort8), 16 edges in flight =================
__global__ __launch_bounds__(256) void k_aggr(const ushort* __restrict__ Y,
    const ushort* __restrict__ R, const float* __restrict__ brel,
    const int* __restrict__ rowptr, const int* __restrict__ degarr, const int* __restrict__ csr,
    ushort* __restrict__ hout, int do_relu){
  int node = blockIdx.x*4 + (threadIdx.x>>6);
  if (node >= NN) return;
  int lane = threadIdx.x & 63;
  int g = lane >> 3;
  int c8 = (lane & 7) << 3;
  int beg = rowptr[node];
  int dc = degarr[node];
  const int* lst = csr + beg;
  float a[8] = {0.f,0.f,0.f,0.f,0.f,0.f,0.f,0.f};
  int i = g;
  for (; i + 8 < dc; i += 16){          // pair: 16 edges in flight per wave
    int s0 = lst[i], s1 = lst[i+8];
    ushort8v y0 = *(const ushort8v*)&Y[((size_t)s0<<6) + c8];
    ushort8v y1 = *(const ushort8v*)&Y[((size_t)s1<<6) + c8];
    #pragma unroll
    for (int j=0;j<8;j++) a[j] += b2f(y0[j]) + b2f(y1[j]);
  }
  if (i < dc){
    int s0 = lst[i];
    ushort8v y0 = *(const ushort8v*)&Y[((size_t)s0<<6) + c8];
    #pragma unroll
    for (int j=0;j<8;j++) a[j] += b2f(y0[j]);
  }
  #pragma unroll
  for (int j=0;j<8;j++){
    a[j] += __shfl_xor(a[j], 8);
    a[j] += __shfl_xor(a[j], 16);
    a[j] += __shfl_xor(a[j], 32);
  }
  if (g == 0){
    ushort8v r8 = *(const ushort8v*)&R[((size_t)node<<6) + c8];
    float4 b0 = *(const float4*)&brel[c8];
    float4 b1 = *(const float4*)&brel[c8+4];
    float bb[8] = {b0.x,b0.y,b0.z,b0.w,b1.x,b1.y,b1.z,b1.w};
    ushort8v o;
    #pragma unroll
    for (int j=0;j<8;j++){
      float v = a[j] + b2f(r8[j]) + bb[j];
      if (do_relu) v = fmaxf(v, 0.f);
      o[j] = f2b(v);
    }
    *(ushort8v*)&hout[((size_t)node<<6) + c8] = o;
  }
}

// ================= pooling + final linear fused =================
__global__ __launch_bounds__(256) void k_pool(const ushort* __restrict__ h, const int* __restrict__ batch,
                       const float* __restrict__ Wlin, const float* __restrict__ blin,
                       float* __restrict__ out){
  int g = blockIdx.x;
  int lo=0, hi=NN;
  while (lo<hi){ int mid=(lo+hi)>>1; if (batch[mid] < g) lo=mid+1; else hi=mid; }
  int beg = lo;
  lo=0; hi=NN;
  while (lo<hi){ int mid=(lo+hi)>>1; if (batch[mid] < g+1) lo=mid+1; else hi=mid; }
  int end = lo;
  int lane = threadIdx.x & 63;
  int w = threadIdx.x >> 6;
  float acc = 0.f;
  for (int n = beg + w; n < end; n += 4) acc += b2f(h[(size_t)n*64 + lane]);
  __shared__ float red[4][64];
  __shared__ float p[64];
  red[w][lane] = acc;
  __syncthreads();
  if (w == 0){
    float v = red[0][lane]+red[1][lane]+red[2][lane]+red[3][lane];
    int cnt = end - beg;
    p[lane] = v / fmaxf((float)cnt, 1.f);
  }
  __syncthreads();
  if (w == 0){
    float o = blin[lane];
    #pragma unroll 8
    for (int k=0;k<64;k++) o += p[k]*Wlin[k*64+lane];
    out[g*64+lane] = o;
  }
}

extern "C" void kernel_launch(void* const* d_in, const int* in_sizes, int n_in,
                              void* d_out, int out_size, void* d_ws, size_t ws_size,
                              hipStream_t stream){
  const float* x     = (const float*)d_in[0];
  const int*   ei    = (const int*)  d_in[1];
  const int*   batch = (const int*)  d_in[2];
  const float* Wrel1 = (const float*)d_in[3];
  const float* brel1 = (const float*)d_in[4];
  const float* Wroot1= (const float*)d_in[5];
  const float* Wrel2 = (const float*)d_in[6];
  const float* brel2 = (const float*)d_in[7];
  const float* Wroot2= (const float*)d_in[8];
  const float* Wrel3 = (const float*)d_in[9];
  const float* brel3 = (const float*)d_in[10];
  const float* Wroot3= (const float*)d_in[11];
  const float* Wlin  = (const float*)d_in[12];
  const float* blin  = (const float*)d_in[13];
  const int* src = ei;
  const int* dst = ei + NE;

  char* wsB = (char*)d_ws;
  size_t off = 0;
  auto alloc = [&](size_t bytes)->void*{
    void* p = wsB + off; off = (off + bytes + 255) & ~(size_t)255; return p;
  };
  int*      csr    = (int*)     alloc((size_t)NBK*BCAP*4);    // 7.2 MB bucket-padded
  unsigned* ebuf   = (unsigned*)alloc((size_t)NBK*BCAP*4);    // 7.2 MB bucket-padded
  int*      rowptr = (int*)     alloc((size_t)NN*4);
  int*      degarr = (int*)     alloc((size_t)NN*4);
  int*      gcur   = (int*)     alloc(NBK*4);
  ushort*   wp     = (ushort*)  alloc((size_t)3*8192*2);      // 48 KB
  ushort*   Y      = (ushort*)  alloc((size_t)NN*64*2);       // 12.8 MB
  ushort*   R      = (ushort*)  alloc((size_t)NN*64*2);       // 12.8 MB
  ushort*   h1     = (ushort*)  alloc((size_t)NN*64*2);       // 12.8 MB
  ushort*   h2     = (ushort*)  alloc((size_t)NN*64*2);       // 12.8 MB

  hipMemsetAsync(gcur, 0, NBK*4, stream);
  // kernel 1: bscatter || wpack
  k_build1<<<NSB + 49, 512, 0, stream>>>(src, dst, gcur, ebuf,
                                         Wrel1,Wroot1,Wrel2,Wroot2,Wrel3,Wroot3, wp);
  // kernel 2: bfill || gemm layer 1
  k_build2_gemm1<<<NBK + G1T, 512, 0, stream>>>(ebuf, gcur, rowptr, degarr, csr,
                                                x, wp + 0*8192, Y, R);

  int gb = (NN+63)/64;
  int ab = (NN+3)/4;

  k_aggr     <<<ab,256,0,stream>>>(Y, R, brel1, rowptr, degarr, csr, h1, 1);
  k_gemm_mfma<<<gb,256,0,stream>>>(h1, wp + 1*8192, Y, R);
  k_aggr     <<<ab,256,0,stream>>>(Y, R, brel2, rowptr, degarr, csr, h2, 1);
  k_gemm_mfma<<<gb,256,0,stream>>>(h2, wp + 2*8192, Y, R);
  k_aggr     <<<ab,256,0,stream>>>(Y, R, brel3, rowptr, degarr, csr, h1, 0);

  k_pool <<<NG,256,0,stream>>>(h1, batch, Wlin, blin, (float*)d_out);
}